// Round 15
// baseline (12761.446 us; speedup 1.0000x reference)
//
#include <hip/hip_runtime.h>
#include <math.h>

#define D 256
#define SEQ 1000
#define NB 32
#define PATCH 160
#define NL 6
#define M_TOTAL (NB * SEQ)   // 32000
#define G3 (3 * D)           // 768

__device__ __forceinline__ float gelu_exact(float v) {
    return 0.5f * v * (1.0f + erff(v * 0.70710678118654752440f));
}

// Raw workgroup barrier: orders LDS (lgkmcnt) but does NOT drain vmcnt.
// (Harness-verified in rounds 3, 6, 7, 9, 10, 11, 12, 13.)
__device__ __forceinline__ void bar_lds() {
    asm volatile("s_waitcnt lgkmcnt(0)" ::: "memory");
    __builtin_amdgcn_s_barrier();
    asm volatile("" ::: "memory");
}

// Packed dot2 (r13-proven): acc += w.lo16*h.lo16 + w.hi16*h.hi16.
// "v" constraint — r14 showed VOP3P cannot source AGPRs on gfx950. This
// round avoids the AGPR spill entirely by halving per-thread pressure
// (96 containers @ 1024 threads), so "v" is satisfied by arch VGPRs
// with no v_accvgpr_read moves.
#define DOT(acc, w, h) asm("v_dot2_f32_f16 %0, %1, %2, %0" \
                           : "+v"(acc) : "v"(w), "v"(h))

// ---------------------------------------------------------------------------
// Kernel 1: conv patchify GEMM + exact GELU + pos_emb add
// ---------------------------------------------------------------------------
__global__ __launch_bounds__(256) void conv_gelu_pos(
    const float* __restrict__ wav, const float* __restrict__ cw,
    const float* __restrict__ pos, float* __restrict__ x)
{
    __shared__ float As[64][33];
    __shared__ float Bs[32][65];
    const int m0 = blockIdx.x * 64;
    const int n0 = blockIdx.y * 64;
    const int tid = threadIdx.x;
    const int tx = tid & 15;      // 0..15 -> n
    const int ty = tid >> 4;      // 0..15 -> m
    float acc[4][4] = {};

    for (int kc = 0; kc < PATCH; kc += 32) {
        for (int p = 0; p < 8; ++p) {
            int mr = p * 8 + (tid >> 5);
            int kk = tid & 31;
            int m = m0 + mr;
            int b = m / SEQ, s = m % SEQ;
            As[mr][kk] = wav[(size_t)b * 160000 + (size_t)s * PATCH + kc + kk];
        }
        for (int p = 0; p < 8; ++p) {
            int kr = p * 4 + (tid >> 6);
            int nn = tid & 63;
            Bs[kr][nn] = cw[(size_t)(kc + kr) * D + n0 + nn];
        }
        __syncthreads();
        #pragma unroll
        for (int kk = 0; kk < 32; ++kk) {
            float a[4], bb[4];
            #pragma unroll
            for (int i = 0; i < 4; ++i) a[i] = As[ty * 4 + i][kk];
            #pragma unroll
            for (int j = 0; j < 4; ++j) bb[j] = Bs[kk][tx * 4 + j];
            #pragma unroll
            for (int i = 0; i < 4; ++i)
                #pragma unroll
                for (int j = 0; j < 4; ++j)
                    acc[i][j] = fmaf(a[i], bb[j], acc[i][j]);
        }
        __syncthreads();
    }
    #pragma unroll
    for (int i = 0; i < 4; ++i) {
        int m = m0 + ty * 4 + i;
        int s = m % SEQ;
        int n = n0 + tx * 4;
        float4 v;
        v.x = gelu_exact(acc[i][0]) + pos[(size_t)s * D + n + 0];
        v.y = gelu_exact(acc[i][1]) + pos[(size_t)s * D + n + 1];
        v.z = gelu_exact(acc[i][2]) + pos[(size_t)s * D + n + 2];
        v.w = gelu_exact(acc[i][3]) + pos[(size_t)s * D + n + 3];
        *(float4*)&x[(size_t)m * D + n] = v;
    }
}

// ---------------------------------------------------------------------------
// Kernel 2: per-row mean / rstd (LayerNorm stats). One wave per row.
// ---------------------------------------------------------------------------
__global__ __launch_bounds__(64) void row_stats(
    const float* __restrict__ x, float* __restrict__ st)
{
    const int m = blockIdx.x;
    const int t = threadIdx.x;
    const float* r = x + (size_t)m * D;
    float s = 0.f, q = 0.f;
    #pragma unroll
    for (int i = 0; i < 4; ++i) {
        float v = r[t + 64 * i];
        s += v;
        q += v * v;
    }
    #pragma unroll
    for (int o = 32; o > 0; o >>= 1) {
        s += __shfl_down(s, o);
        q += __shfl_down(q, o);
    }
    if (t == 0) {
        float mu = s * (1.f / 256.f);
        float var = q * (1.f / 256.f) - mu * mu;
        st[2 * m]     = mu;
        st[2 * m + 1] = rsqrtf(var + 1e-5f);
    }
}

// ---------------------------------------------------------------------------
// Kernel 3: fused LN + input-projection GEMM
// ---------------------------------------------------------------------------
__global__ __launch_bounds__(256) void ln_xp_gemm(
    const float* __restrict__ x, const float* __restrict__ st,
    const float* __restrict__ lnsc, const float* __restrict__ lnbi,
    const float* __restrict__ wih, const float* __restrict__ bih,
    float* __restrict__ xp)
{
    __shared__ float As[64][33];
    __shared__ float Bs[32][65];
    __shared__ float sc[D], bi[D];
    const int m0 = blockIdx.x * 64;
    const int n0 = blockIdx.y * 64;
    const int tid = threadIdx.x;
    const int tx = tid & 15;
    const int ty = tid >> 4;
    sc[tid] = lnsc[tid];
    bi[tid] = lnbi[tid];
    float acc[4][4] = {};

    for (int kc = 0; kc < D; kc += 32) {
        for (int p = 0; p < 8; ++p) {
            int mr = p * 8 + (tid >> 5);
            int kk = tid & 31;
            int m = m0 + mr;
            float mu = st[2 * m], rs = st[2 * m + 1];
            float v = x[(size_t)m * D + kc + kk];
            As[mr][kk] = (v - mu) * rs * sc[kc + kk] + bi[kc + kk];
        }
        for (int p = 0; p < 8; ++p) {
            int nr = p * 8 + (tid >> 5);
            int kk = tid & 31;
            Bs[kk][nr] = wih[(size_t)(n0 + nr) * D + kc + kk];
        }
        __syncthreads();
        #pragma unroll
        for (int kk = 0; kk < 32; ++kk) {
            float a[4], bb[4];
            #pragma unroll
            for (int i = 0; i < 4; ++i) a[i] = As[ty * 4 + i][kk];
            #pragma unroll
            for (int j = 0; j < 4; ++j) bb[j] = Bs[kk][tx * 4 + j];
            #pragma unroll
            for (int i = 0; i < 4; ++i)
                #pragma unroll
                for (int j = 0; j < 4; ++j)
                    acc[i][j] = fmaf(a[i], bb[j], acc[i][j]);
        }
        __syncthreads();
    }
    #pragma unroll
    for (int i = 0; i < 4; ++i) {
        int m = m0 + ty * 4 + i;
        int n = n0 + tx * 4;
        float4 v;
        v.x = acc[i][0] + bih[n + 0];
        v.y = acc[i][1] + bih[n + 1];
        v.z = acc[i][2] + bih[n + 2];
        v.w = acc[i][3] + bih[n + 3];
        *(float4*)&xp[(size_t)m * G3 + n] = v;
    }
}

// ---------------------------------------------------------------------------
// Kernel 4: pack w_hh fp32 -> fp16 pairs for the 4-way k-split:
// word [kq][s][d] (u32 = 2 fp16), s = gate*32 + j covers k = kq*64 + 2j,
// 2j+1 for output dim d. out[((kq*96)+s)*256 + d]  (4*96*256 u32 = 384 KB)
// ---------------------------------------------------------------------------
__global__ __launch_bounds__(256) void pack_whh(
    const float* __restrict__ whh, unsigned int* __restrict__ wh16)
{
    const int b  = blockIdx.x;        // 0..383
    const int kq = b / 96;            // k quarter
    const int s  = b % 96;
    const int gi = s / 32;            // gate 0=r 1=z 2=n
    const int j  = s % 32;            // k-pair index within quarter
    const int d  = threadIdx.x;       // output dim
    const size_t row = (size_t)(gi * D + d) * D + kq * 64 + 2 * j;
    unsigned short lo = __builtin_bit_cast(unsigned short, (_Float16)whh[row]);
    unsigned short hi = __builtin_bit_cast(unsigned short, (_Float16)whh[row + 1]);
    wh16[(size_t)(kq * 96 + s) * 256 + d] = (unsigned int)lo | ((unsigned int)hi << 16);
}

// ---------------------------------------------------------------------------
// Kernel 5: GRU recurrence — SINGLE block per batch, 1024 threads, fp16
// weights in ARCH VGPRs (96 containers/thread), v_dot2_f32_f16.
//
// Round-13/14 post-mortem: at 512 threads the 192 containers + ~50 working
// exceeded the allocator's arch-VGPR comfort -> AGPR spill -> 192
// v_accvgpr_read per step (r13, 3290cy/step); VOP3P cannot source AGPRs
// directly (r14 compile fail). Fix: 1024 threads -> 4-way k-split ->
// 96 containers + ~50 working ~= 150 << 256 -> arch-resident, ZERO moves.
// Issue floor: 4 waves/SIMD x 96 dot2 x 2cy = 768cy/step.
// All r13-proven pieces kept verbatim: DOT macro, fp16-h pack via shfl,
// LDS-broadcast hp reads, khalf-style LDS reduce (now 4-way, matching
// r7's passing 4-quarter combine order), 2 bar_lds/step, no atomics.
// ---------------------------------------------------------------------------
__global__ __launch_bounds__(1024, 1) void gru_scan_regs(
    const float* __restrict__ xp, const unsigned int* __restrict__ wh16,
    const float* __restrict__ bhh, float* __restrict__ x)
{
    __shared__ float h_lds[D];                       // fp32 h(t)
    __shared__ __align__(16) unsigned int h16_lds[D / 2];  // packed fp16 pairs
    __shared__ float pr[3][3][D];                    // kq1..3 partials [kq-1][gate][d]
    const int tid = threadIdx.x;
    const int d   = tid & 255;
    const int kq  = tid >> 8;           // 0..3 (wave-uniform)
    const int batch = blockIdx.x;

    // --- resident weights: 6 x 16 float-containers (= 192 fp16), coalesced -
    // gate g, pair j (k = kq*64 + 2j, 2j+1): j<16 -> A[j], j>=16 -> B[j-16]
    float wrA[16], wrB[16], wzA[16], wzB[16], wnA[16], wnB[16];
    {
        const unsigned int* wb = wh16 + (size_t)kq * 96 * 256 + d;
        #pragma unroll
        for (int j = 0; j < 16; ++j) wrA[j] = __uint_as_float(wb[(size_t)(0 * 32 + j) * 256]);
        #pragma unroll
        for (int j = 0; j < 16; ++j) wrB[j] = __uint_as_float(wb[(size_t)(0 * 32 + 16 + j) * 256]);
        #pragma unroll
        for (int j = 0; j < 16; ++j) wzA[j] = __uint_as_float(wb[(size_t)(1 * 32 + j) * 256]);
        #pragma unroll
        for (int j = 0; j < 16; ++j) wzB[j] = __uint_as_float(wb[(size_t)(1 * 32 + 16 + j) * 256]);
        #pragma unroll
        for (int j = 0; j < 16; ++j) wnA[j] = __uint_as_float(wb[(size_t)(2 * 32 + j) * 256]);
        #pragma unroll
        for (int j = 0; j < 16; ++j) wnB[j] = __uint_as_float(wb[(size_t)(2 * 32 + 16 + j) * 256]);
    }
    const float bh_r = bhh[d];
    const float bh_z = bhh[D + d];
    const float bh_n = bhh[2 * D + d];

    const float* xpb = xp + (size_t)batch * SEQ * G3;
    float* xb = x + (size_t)batch * SEQ * D;

    if (tid < D) h_lds[tid] = 0.f;
    if (tid < D / 2) h16_lds[tid] = 0u;
    __syncthreads();

    const unsigned int* hp_base = &h16_lds[kq * 32];  // this quarter's 32 pairs
    for (int t = 0; t < SEQ; ++t) {
        // issue xp + residual loads early; latency hides under the DOT phase
        float xr = 0.f, xz = 0.f, xn_ = 0.f, xold = 0.f;
        if (kq == 0) {
            const float* xpt = xpb + (size_t)t * G3;
            xr   = xpt[d];
            xz   = xpt[D + d];
            xn_  = xpt[2 * D + d];
            xold = xb[(size_t)t * D + d];
        }

        // --- DOT phase: 96 v_dot2_f32_f16 against arch-resident fp16 -------
        float ar = 0.f, az = 0.f, an = 0.f;
        #pragma unroll
        for (int c = 0; c < 4; ++c) {          // pairs j = 4c .. 4c+3 (A half)
            uint4 hp = *(const uint4*)(hp_base + 4 * c);   // uniform bcast
            DOT(ar, wrA[4*c+0], hp.x); DOT(ar, wrA[4*c+1], hp.y);
            DOT(ar, wrA[4*c+2], hp.z); DOT(ar, wrA[4*c+3], hp.w);
            DOT(az, wzA[4*c+0], hp.x); DOT(az, wzA[4*c+1], hp.y);
            DOT(az, wzA[4*c+2], hp.z); DOT(az, wzA[4*c+3], hp.w);
            DOT(an, wnA[4*c+0], hp.x); DOT(an, wnA[4*c+1], hp.y);
            DOT(an, wnA[4*c+2], hp.z); DOT(an, wnA[4*c+3], hp.w);
        }
        #pragma unroll
        for (int c = 0; c < 4; ++c) {          // pairs j = 16+4c .. (B half)
            uint4 hp = *(const uint4*)(hp_base + 16 + 4 * c);
            DOT(ar, wrB[4*c+0], hp.x); DOT(ar, wrB[4*c+1], hp.y);
            DOT(ar, wrB[4*c+2], hp.z); DOT(ar, wrB[4*c+3], hp.w);
            DOT(az, wzB[4*c+0], hp.x); DOT(az, wzB[4*c+1], hp.y);
            DOT(az, wzB[4*c+2], hp.z); DOT(az, wzB[4*c+3], hp.w);
            DOT(an, wnB[4*c+0], hp.x); DOT(an, wnB[4*c+1], hp.y);
            DOT(an, wnB[4*c+2], hp.z); DOT(an, wnB[4*c+3], hp.w);
        }
        if (kq) { pr[kq-1][0][d] = ar; pr[kq-1][1][d] = az; pr[kq-1][2][d] = an; }
        bar_lds();

        // --- finalize: combine quarters (fixed order), gates, update -------
        if (kq == 0) {
            ar += pr[0][0][d] + pr[1][0][d] + pr[2][0][d];
            az += pr[0][1][d] + pr[1][1][d] + pr[2][1][d];
            an += pr[0][2][d] + pr[1][2][d] + pr[2][2][d];
            float gr = xr + ar + bh_r;
            float gz = xz + az + bh_z;
            float gn =      an + bh_n;
            float r = 1.f / (1.f + expf(-gr));
            float z = 1.f / (1.f + expf(-gz));
            float n = tanhf(xn_ + r * gn);
            float hnew = (1.f - z) * n + z * h_lds[d];
            h_lds[d] = hnew;
            // pack (h[d], h[d+1]) -> fp16 pair; neighbors are adjacent lanes
            float hn1 = __shfl_down(hnew, 1);
            if (!(d & 1)) {
                unsigned short l0 = __builtin_bit_cast(unsigned short, (_Float16)hnew);
                unsigned short l1 = __builtin_bit_cast(unsigned short, (_Float16)hn1);
                h16_lds[d >> 1] = (unsigned int)l0 | ((unsigned int)l1 << 16);
            }
            xb[(size_t)t * D + d] = xold + hnew;
        }
        bar_lds();
    }
}

// ---------------------------------------------------------------------------
// Kernel 6: final LN + mean-pool over sequence
// ---------------------------------------------------------------------------
__global__ __launch_bounds__(256) void pool_ln(
    const float* __restrict__ x, const float* __restrict__ st,
    const float* __restrict__ fsc, const float* __restrict__ fbi,
    float* __restrict__ emb)
{
    const int b = blockIdx.x;
    const int d = threadIdx.x;
    float acc = 0.f;
    for (int s = 0; s < SEQ; ++s) {
        int m = b * SEQ + s;
        acc += (x[(size_t)m * D + d] - st[2 * m]) * st[2 * m + 1];
    }
    emb[b * D + d] = (acc * (1.f / (float)SEQ)) * fsc[d] + fbi[d];
}

// ---------------------------------------------------------------------------
// Kernel 7: classification head (tiny). Single block.
// ---------------------------------------------------------------------------
__global__ __launch_bounds__(256) void head_mlp(
    const float* __restrict__ emb, const float* __restrict__ w1,
    const float* __restrict__ b1, const float* __restrict__ w2,
    const float* __restrict__ b2, float* __restrict__ out)
{
    __shared__ float es[NB][D + 1];
    __shared__ float h1[NB][128 + 1];
    const int t = threadIdx.x;
    for (int i = t; i < NB * D; i += 256) es[i / D][i % D] = emb[i];
    __syncthreads();
    for (int i = t; i < NB * 128; i += 256) {
        int bb = i / 128, j = i % 128;
        float a = b1[j];
        for (int k = 0; k < D; ++k) a = fmaf(es[bb][k], w1[(size_t)k * 128 + j], a);
        h1[bb][j] = gelu_exact(a);
    }
    __syncthreads();
    for (int i = t; i < NB * 8; i += 256) {
        int bb = i / 8, c = i % 8;
        float a = b2[c];
        for (int k = 0; k < 128; ++k) a = fmaf(h1[bb][k], w2[(size_t)k * 8 + c], a);
        out[i] = a;
    }
}

// ---------------------------------------------------------------------------
extern "C" void kernel_launch(void* const* d_in, const int* in_sizes, int n_in,
                              void* d_out, int out_size, void* d_ws, size_t ws_size,
                              hipStream_t stream)
{
    const float* wav  = (const float*)d_in[0];
    const float* cw   = (const float*)d_in[1];
    const float* pos  = (const float*)d_in[2];
    const float* lnsc = (const float*)d_in[3];
    const float* lnbi = (const float*)d_in[4];
    const float* wih  = (const float*)d_in[5];
    const float* whh  = (const float*)d_in[6];
    const float* bih  = (const float*)d_in[7];
    const float* bhh  = (const float*)d_in[8];
    const float* fsc  = (const float*)d_in[9];
    const float* fbi  = (const float*)d_in[10];
    const float* hw1  = (const float*)d_in[11];
    const float* hb1  = (const float*)d_in[12];
    const float* hw2  = (const float*)d_in[13];
    const float* hb2  = (const float*)d_in[14];

    float* ws    = (float*)d_ws;
    float* x     = ws;                        // 8,192,000 f
    float* xp    = x + (size_t)M_TOTAL * D;   // 24,576,000 f
    float* st    = xp + (size_t)M_TOTAL * G3; // 64,000 f
    unsigned int* wh16 = (unsigned int*)(st + 2 * M_TOTAL); // 98,304 u32
    float* emb   = (float*)(wh16 + 98304);    // 8,192 f

    conv_gelu_pos<<<dim3(M_TOTAL / 64, D / 64), 256, 0, stream>>>(wav, cw, pos, x);

    for (int l = 0; l < NL; ++l) {
        row_stats<<<M_TOTAL, 64, 0, stream>>>(x, st);
        ln_xp_gemm<<<dim3(M_TOTAL / 64, G3 / 64), 256, 0, stream>>>(
            x, st, lnsc + (size_t)l * D, lnbi + (size_t)l * D,
            wih + (size_t)l * G3 * D, bih + (size_t)l * G3, xp);
        pack_whh<<<384, 256, 0, stream>>>(whh + (size_t)l * G3 * D, wh16);
        gru_scan_regs<<<NB, 1024, 0, stream>>>(
            xp, wh16, bhh + (size_t)l * G3, x);
    }

    row_stats<<<M_TOTAL, 64, 0, stream>>>(x, st);
    pool_ln<<<NB, D, 0, stream>>>(x, st, fsc, fbi, emb);
    head_mlp<<<1, 256, 0, stream>>>(emb, hw1, hb1, hw2, hb2, (float*)d_out);
}

// Round 16
// 9276.778 us; speedup vs baseline: 1.3756x; 1.3756x over previous
//
#include <hip/hip_runtime.h>
#include <math.h>

#define D 256
#define SEQ 1000
#define NB 32
#define PATCH 160
#define NL 6
#define M_TOTAL (NB * SEQ)   // 32000
#define G3 (3 * D)           // 768

typedef _Float16 half8 __attribute__((ext_vector_type(8)));
typedef float f32x4 __attribute__((ext_vector_type(4)));

__device__ __forceinline__ float gelu_exact(float v) {
    return 0.5f * v * (1.0f + erff(v * 0.70710678118654752440f));
}

// Raw workgroup barrier: orders LDS (lgkmcnt) but does NOT drain vmcnt.
// (Harness-verified in rounds 3, 6, 7, 9, 10, 11, 12, 13.)
__device__ __forceinline__ void bar_lds() {
    asm volatile("s_waitcnt lgkmcnt(0)" ::: "memory");
    __builtin_amdgcn_s_barrier();
    asm volatile("" ::: "memory");
}

// ---------------------------------------------------------------------------
// Kernel 1: conv patchify GEMM + exact GELU + pos_emb add
// ---------------------------------------------------------------------------
__global__ __launch_bounds__(256) void conv_gelu_pos(
    const float* __restrict__ wav, const float* __restrict__ cw,
    const float* __restrict__ pos, float* __restrict__ x)
{
    __shared__ float As[64][33];
    __shared__ float Bs[32][65];
    const int m0 = blockIdx.x * 64;
    const int n0 = blockIdx.y * 64;
    const int tid = threadIdx.x;
    const int tx = tid & 15;      // 0..15 -> n
    const int ty = tid >> 4;      // 0..15 -> m
    float acc[4][4] = {};

    for (int kc = 0; kc < PATCH; kc += 32) {
        for (int p = 0; p < 8; ++p) {
            int mr = p * 8 + (tid >> 5);
            int kk = tid & 31;
            int m = m0 + mr;
            int b = m / SEQ, s = m % SEQ;
            As[mr][kk] = wav[(size_t)b * 160000 + (size_t)s * PATCH + kc + kk];
        }
        for (int p = 0; p < 8; ++p) {
            int kr = p * 4 + (tid >> 6);
            int nn = tid & 63;
            Bs[kr][nn] = cw[(size_t)(kc + kr) * D + n0 + nn];
        }
        __syncthreads();
        #pragma unroll
        for (int kk = 0; kk < 32; ++kk) {
            float a[4], bb[4];
            #pragma unroll
            for (int i = 0; i < 4; ++i) a[i] = As[ty * 4 + i][kk];
            #pragma unroll
            for (int j = 0; j < 4; ++j) bb[j] = Bs[kk][tx * 4 + j];
            #pragma unroll
            for (int i = 0; i < 4; ++i)
                #pragma unroll
                for (int j = 0; j < 4; ++j)
                    acc[i][j] = fmaf(a[i], bb[j], acc[i][j]);
        }
        __syncthreads();
    }
    #pragma unroll
    for (int i = 0; i < 4; ++i) {
        int m = m0 + ty * 4 + i;
        int s = m % SEQ;
        int n = n0 + tx * 4;
        float4 v;
        v.x = gelu_exact(acc[i][0]) + pos[(size_t)s * D + n + 0];
        v.y = gelu_exact(acc[i][1]) + pos[(size_t)s * D + n + 1];
        v.z = gelu_exact(acc[i][2]) + pos[(size_t)s * D + n + 2];
        v.w = gelu_exact(acc[i][3]) + pos[(size_t)s * D + n + 3];
        *(float4*)&x[(size_t)m * D + n] = v;
    }
}

// ---------------------------------------------------------------------------
// Kernel 2: per-row mean / rstd (LayerNorm stats). One wave per row.
// ---------------------------------------------------------------------------
__global__ __launch_bounds__(64) void row_stats(
    const float* __restrict__ x, float* __restrict__ st)
{
    const int m = blockIdx.x;
    const int t = threadIdx.x;
    const float* r = x + (size_t)m * D;
    float s = 0.f, q = 0.f;
    #pragma unroll
    for (int i = 0; i < 4; ++i) {
        float v = r[t + 64 * i];
        s += v;
        q += v * v;
    }
    #pragma unroll
    for (int o = 32; o > 0; o >>= 1) {
        s += __shfl_down(s, o);
        q += __shfl_down(q, o);
    }
    if (t == 0) {
        float mu = s * (1.f / 256.f);
        float var = q * (1.f / 256.f) - mu * mu;
        st[2 * m]     = mu;
        st[2 * m + 1] = rsqrtf(var + 1e-5f);
    }
}

// ---------------------------------------------------------------------------
// Kernel 3: fused LN + input-projection GEMM
// ---------------------------------------------------------------------------
__global__ __launch_bounds__(256) void ln_xp_gemm(
    const float* __restrict__ x, const float* __restrict__ st,
    const float* __restrict__ lnsc, const float* __restrict__ lnbi,
    const float* __restrict__ wih, const float* __restrict__ bih,
    float* __restrict__ xp)
{
    __shared__ float As[64][33];
    __shared__ float Bs[32][65];
    __shared__ float sc[D], bi[D];
    const int m0 = blockIdx.x * 64;
    const int n0 = blockIdx.y * 64;
    const int tid = threadIdx.x;
    const int tx = tid & 15;
    const int ty = tid >> 4;
    sc[tid] = lnsc[tid];
    bi[tid] = lnbi[tid];
    float acc[4][4] = {};

    for (int kc = 0; kc < D; kc += 32) {
        for (int p = 0; p < 8; ++p) {
            int mr = p * 8 + (tid >> 5);
            int kk = tid & 31;
            int m = m0 + mr;
            float mu = st[2 * m], rs = st[2 * m + 1];
            float v = x[(size_t)m * D + kc + kk];
            As[mr][kk] = (v - mu) * rs * sc[kc + kk] + bi[kc + kk];
        }
        for (int p = 0; p < 8; ++p) {
            int nr = p * 8 + (tid >> 5);
            int kk = tid & 31;
            Bs[kk][nr] = wih[(size_t)(n0 + nr) * D + kc + kk];
        }
        __syncthreads();
        #pragma unroll
        for (int kk = 0; kk < 32; ++kk) {
            float a[4], bb[4];
            #pragma unroll
            for (int i = 0; i < 4; ++i) a[i] = As[ty * 4 + i][kk];
            #pragma unroll
            for (int j = 0; j < 4; ++j) bb[j] = Bs[kk][tx * 4 + j];
            #pragma unroll
            for (int i = 0; i < 4; ++i)
                #pragma unroll
                for (int j = 0; j < 4; ++j)
                    acc[i][j] = fmaf(a[i], bb[j], acc[i][j]);
        }
        __syncthreads();
    }
    #pragma unroll
    for (int i = 0; i < 4; ++i) {
        int m = m0 + ty * 4 + i;
        int n = n0 + tx * 4;
        float4 v;
        v.x = acc[i][0] + bih[n + 0];
        v.y = acc[i][1] + bih[n + 1];
        v.z = acc[i][2] + bih[n + 2];
        v.w = acc[i][3] + bih[n + 3];
        *(float4*)&xp[(size_t)m * G3 + n] = v;
    }
}

// ---------------------------------------------------------------------------
// Kernel 4: pack w_hh fp32 -> fp16 MFMA B-fragments.
// Tile t (n0=16t, n = gate*256+d over 768), chunk c (k0=32c), lane l, word j:
//   element k = 32c + 8*(l>>4) + 2j,2j+1 ; col n = 16t + (l&15)
//   out[((t*8 + c)*64 + l)*4 + j] = pack(W[n][k], W[n][k+1])   (whh row-major)
// 48*8*64*4 = 98304 u32 = 384 KB. Lane-contiguous uint4 -> coalesced loads.
// ---------------------------------------------------------------------------
__global__ __launch_bounds__(256) void pack_whh(
    const float* __restrict__ whh, unsigned int* __restrict__ wfrag)
{
    const int idx = blockIdx.x * 256 + threadIdx.x;   // 0..98303
    const int j = idx & 3;
    const int l = (idx >> 2) & 63;
    const int c = (idx >> 8) & 7;
    const int t = idx >> 11;                          // 0..47
    const int n = t * 16 + (l & 15);
    const int k = c * 32 + (l >> 4) * 8 + 2 * j;
    unsigned short lo = __builtin_bit_cast(unsigned short, (_Float16)whh[(size_t)n * D + k]);
    unsigned short hi = __builtin_bit_cast(unsigned short, (_Float16)whh[(size_t)n * D + k + 1]);
    wfrag[idx] = (unsigned int)lo | ((unsigned int)hi << 16);
}

// ---------------------------------------------------------------------------
// Kernel 5: GRU recurrence — SINGLE block per batch, W_hh as AGPR-resident
// MFMA B-fragments. The matmul runs on the MATRIX pipe.
//
// r13-r15 post-mortem: the allocator parks 192 weight words in AGPRs and
// VOP3P (dot2) cannot read AGPRs -> permanent 192-move tax (r13 3290cy/
// step); shrinking per-thread pressure shrinks the budget equally (r15).
// MFMA reads A/B from AGPRs NATIVELY (isa §10) -> the parking is free.
// Formulation: out[768] = W^T(768x256) . h; N=768 as 48 16-wide tiles,
// K=256 as 8 32-chunks; mfma_f32_16x16x32_f16; A = h replicated over all
// 16 rows (broadcast ds_read per lane-group; row-mapping irrelevant by
// replication; A/B share the k-mapping formula so a uniform mapping error
// cancels in the contraction). All C rows identical -> lanes 0..15 write
// reg0 (col=l&15, row 0 per verified C-layout) to gate_lds. K-reduction
// happens INSIDE the MFMA -> no pr[] partial exchange at all.
// Per wave: 6 tiles x 8 chunks = 48 MFMA -> matrix pipe ~466cy/step.
// Gates/pack = r13 verbatim (fp16 h pack via shfl, fp32 h state, 2
// bar_lds, no atomics, hang-impossible).
// ---------------------------------------------------------------------------
__global__ __launch_bounds__(512, 1) void gru_scan_mfma(
    const float* __restrict__ xp, const unsigned int* __restrict__ wfrag,
    const float* __restrict__ bhh, float* __restrict__ x)
{
    __shared__ float h_lds[D];                             // fp32 h(t)
    __shared__ __align__(16) unsigned int h16_lds[D / 2];  // packed fp16 pairs
    __shared__ float gate_lds[G3];                         // W^T.h results
    const int tid  = threadIdx.x;
    const int w    = tid >> 6;          // wave 0..7
    const int l    = tid & 63;          // lane
    const int d    = tid;               // gate thread's output dim (tid<256)
    const int batch = blockIdx.x;

    // --- resident weights: 48 B-fragments = 192 u32/thread, coalesced ------
    half8 bf[6][8];
    {
        #pragma unroll
        for (int i = 0; i < 6; ++i)
            #pragma unroll
            for (int c = 0; c < 8; ++c) {
                const uint4 v = *(const uint4*)(
                    wfrag + ((size_t)(((w * 6 + i) * 8 + c) * 64 + l)) * 4);
                bf[i][c] = __builtin_bit_cast(half8, v);
            }
    }
    float bh_r = 0.f, bh_z = 0.f, bh_n = 0.f;
    if (tid < D) {
        bh_r = bhh[d];
        bh_z = bhh[D + d];
        bh_n = bhh[2 * D + d];
    }

    const float* xpb = xp + (size_t)batch * SEQ * G3;
    float* xb = x + (size_t)batch * SEQ * D;

    if (tid < D) h_lds[tid] = 0.f;
    if (tid < D / 2) h16_lds[tid] = 0u;
    __syncthreads();

    const int lg = l >> 4;              // lane group 0..3
    for (int t = 0; t < SEQ; ++t) {
        // xp + residual loads early (tid<256); latency hides under MFMA
        float xr = 0.f, xz = 0.f, xn_ = 0.f, xold = 0.f;
        if (tid < D) {
            const float* xpt = xpb + (size_t)t * G3;
            xr   = xpt[d];
            xz   = xpt[D + d];
            xn_  = xpt[2 * D + d];
            xold = xb[(size_t)t * D + d];
        }

        // --- A fragments: h replicated across rows; broadcast LDS reads ----
        half8 af[8];
        #pragma unroll
        for (int c = 0; c < 8; ++c)
            af[c] = __builtin_bit_cast(half8,
                *(const uint4*)(h16_lds + 16 * c + 4 * lg));

        // --- MFMA phase: 6 tiles x 8 K-chunks, C accumulates K in-pipe -----
        #pragma unroll
        for (int i = 0; i < 6; ++i) {
            f32x4 cf = {0.f, 0.f, 0.f, 0.f};
            #pragma unroll
            for (int c = 0; c < 8; ++c)
                cf = __builtin_amdgcn_mfma_f32_16x16x32_f16(af[c], bf[i][c], cf, 0, 0, 0);
            if (l < 16) gate_lds[(w * 6 + i) * 16 + l] = cf[0];  // row 0
        }
        bar_lds();

        // --- gates (tid<256): all K already reduced by MFMA ----------------
        if (tid < D) {
            float ar = gate_lds[d];
            float az = gate_lds[D + d];
            float an = gate_lds[2 * D + d];
            float gr = xr + ar + bh_r;
            float gz = xz + az + bh_z;
            float gn =      an + bh_n;
            float r = 1.f / (1.f + expf(-gr));
            float z = 1.f / (1.f + expf(-gz));
            float n = tanhf(xn_ + r * gn);
            float hnew = (1.f - z) * n + z * h_lds[d];
            h_lds[d] = hnew;
            // pack (h[d], h[d+1]) -> fp16 pair; neighbors are adjacent lanes
            float hn1 = __shfl_down(hnew, 1);
            if (!(d & 1)) {
                unsigned short l0 = __builtin_bit_cast(unsigned short, (_Float16)hnew);
                unsigned short l1 = __builtin_bit_cast(unsigned short, (_Float16)hn1);
                h16_lds[d >> 1] = (unsigned int)l0 | ((unsigned int)l1 << 16);
            }
            xb[(size_t)t * D + d] = xold + hnew;
        }
        bar_lds();
    }
}

// ---------------------------------------------------------------------------
// Kernel 6: final LN + mean-pool over sequence
// ---------------------------------------------------------------------------
__global__ __launch_bounds__(256) void pool_ln(
    const float* __restrict__ x, const float* __restrict__ st,
    const float* __restrict__ fsc, const float* __restrict__ fbi,
    float* __restrict__ emb)
{
    const int b = blockIdx.x;
    const int d = threadIdx.x;
    float acc = 0.f;
    for (int s = 0; s < SEQ; ++s) {
        int m = b * SEQ + s;
        acc += (x[(size_t)m * D + d] - st[2 * m]) * st[2 * m + 1];
    }
    emb[b * D + d] = (acc * (1.f / (float)SEQ)) * fsc[d] + fbi[d];
}

// ---------------------------------------------------------------------------
// Kernel 7: classification head (tiny). Single block.
// ---------------------------------------------------------------------------
__global__ __launch_bounds__(256) void head_mlp(
    const float* __restrict__ emb, const float* __restrict__ w1,
    const float* __restrict__ b1, const float* __restrict__ w2,
    const float* __restrict__ b2, float* __restrict__ out)
{
    __shared__ float es[NB][D + 1];
    __shared__ float h1[NB][128 + 1];
    const int t = threadIdx.x;
    for (int i = t; i < NB * D; i += 256) es[i / D][i % D] = emb[i];
    __syncthreads();
    for (int i = t; i < NB * 128; i += 256) {
        int bb = i / 128, j = i % 128;
        float a = b1[j];
        for (int k = 0; k < D; ++k) a = fmaf(es[bb][k], w1[(size_t)k * 128 + j], a);
        h1[bb][j] = gelu_exact(a);
    }
    __syncthreads();
    for (int i = t; i < NB * 8; i += 256) {
        int bb = i / 8, c = i % 8;
        float a = b2[c];
        for (int k = 0; k < 128; ++k) a = fmaf(h1[bb][k], w2[(size_t)k * 8 + c], a);
        out[i] = a;
    }
}

// ---------------------------------------------------------------------------
extern "C" void kernel_launch(void* const* d_in, const int* in_sizes, int n_in,
                              void* d_out, int out_size, void* d_ws, size_t ws_size,
                              hipStream_t stream)
{
    const float* wav  = (const float*)d_in[0];
    const float* cw   = (const float*)d_in[1];
    const float* pos  = (const float*)d_in[2];
    const float* lnsc = (const float*)d_in[3];
    const float* lnbi = (const float*)d_in[4];
    const float* wih  = (const float*)d_in[5];
    const float* whh  = (const float*)d_in[6];
    const float* bih  = (const float*)d_in[7];
    const float* bhh  = (const float*)d_in[8];
    const float* fsc  = (const float*)d_in[9];
    const float* fbi  = (const float*)d_in[10];
    const float* hw1  = (const float*)d_in[11];
    const float* hb1  = (const float*)d_in[12];
    const float* hw2  = (const float*)d_in[13];
    const float* hb2  = (const float*)d_in[14];

    float* ws    = (float*)d_ws;
    float* x     = ws;                        // 8,192,000 f
    float* xp    = x + (size_t)M_TOTAL * D;   // 24,576,000 f
    float* st    = xp + (size_t)M_TOTAL * G3; // 64,000 f
    unsigned int* wfrag = (unsigned int*)(st + 2 * M_TOTAL); // 98,304 u32
    float* emb   = (float*)(wfrag + 98304);   // 8,192 f

    conv_gelu_pos<<<dim3(M_TOTAL / 64, D / 64), 256, 0, stream>>>(wav, cw, pos, x);

    for (int l = 0; l < NL; ++l) {
        row_stats<<<M_TOTAL, 64, 0, stream>>>(x, st);
        ln_xp_gemm<<<dim3(M_TOTAL / 64, G3 / 64), 256, 0, stream>>>(
            x, st, lnsc + (size_t)l * D, lnbi + (size_t)l * D,
            wih + (size_t)l * G3 * D, bih + (size_t)l * G3, xp);
        pack_whh<<<384, 256, 0, stream>>>(whh + (size_t)l * G3 * D, wfrag);
        gru_scan_mfma<<<NB, 512, 0, stream>>>(
            xp, wfrag, bhh + (size_t)l * G3, x);
    }

    row_stats<<<M_TOTAL, 64, 0, stream>>>(x, st);
    pool_ln<<<NB, D, 0, stream>>>(x, st, fsc, fbi, emb);
    head_mlp<<<1, 256, 0, stream>>>(emb, hw1, hb1, hw2, hb2, (float*)d_out);
}

// Round 21
// 8278.284 us; speedup vs baseline: 1.5416x; 1.1206x over previous
//
#include <hip/hip_runtime.h>
#include <math.h>

#define D 256
#define SEQ 1000
#define NB 32
#define PATCH 160
#define NL 6
#define M_TOTAL (NB * SEQ)   // 32000
#define G3 (3 * D)           // 768

typedef _Float16 half8 __attribute__((ext_vector_type(8)));
typedef float f32x4 __attribute__((ext_vector_type(4)));

__device__ __forceinline__ float gelu_exact(float v) {
    return 0.5f * v * (1.0f + erff(v * 0.70710678118654752440f));
}

// Raw workgroup barrier: orders LDS (lgkmcnt) but does NOT drain vmcnt.
// (Harness-verified in rounds 3, 6, 7, 9, 12, 13, 16.)
__device__ __forceinline__ void bar_lds() {
    asm volatile("s_waitcnt lgkmcnt(0)" ::: "memory");
    __builtin_amdgcn_s_barrier();
    asm volatile("" ::: "memory");
}

// Fast sigmoid/tanh on native HW transcendentals (v_exp_f32 is exp2; v_rcp).
// r17 compile fix: __exp2f collides with a glibc math.h macro; the clang
// device builtin for v_exp_f32 is __builtin_amdgcn_exp2f.
// Max error ~1ulp each (~1e-7 rel) — invisible next to the 2.2e-3 fp16-
// weight quantization term. Saturation-safe: g->-inf: exp2(+inf)=inf,
// rcp(inf)=0; g->+inf: exp2(-inf)=0, rcp(1)=1. tanh clamped to +-12 so
// exp2(2*12*log2e)=2^34.6 stays finite -> (t-1)*rcp(t+1) -> 1.
__device__ __forceinline__ float fast_sigmoid(float g) {
    float e = __builtin_amdgcn_exp2f(-1.44269504f * g);
    return __builtin_amdgcn_rcpf(1.f + e);
}
__device__ __forceinline__ float fast_tanh(float a) {
    a = fminf(fmaxf(a, -12.f), 12.f);
    float t = __builtin_amdgcn_exp2f(2.88539008f * a);
    return (t - 1.f) * __builtin_amdgcn_rcpf(t + 1.f);
}

// ---------------------------------------------------------------------------
// Kernel 1: conv patchify GEMM + exact GELU + pos_emb add
// ---------------------------------------------------------------------------
__global__ __launch_bounds__(256) void conv_gelu_pos(
    const float* __restrict__ wav, const float* __restrict__ cw,
    const float* __restrict__ pos, float* __restrict__ x)
{
    __shared__ float As[64][33];
    __shared__ float Bs[32][65];
    const int m0 = blockIdx.x * 64;
    const int n0 = blockIdx.y * 64;
    const int tid = threadIdx.x;
    const int tx = tid & 15;      // 0..15 -> n
    const int ty = tid >> 4;      // 0..15 -> m
    float acc[4][4] = {};

    for (int kc = 0; kc < PATCH; kc += 32) {
        for (int p = 0; p < 8; ++p) {
            int mr = p * 8 + (tid >> 5);
            int kk = tid & 31;
            int m = m0 + mr;
            int b = m / SEQ, s = m % SEQ;
            As[mr][kk] = wav[(size_t)b * 160000 + (size_t)s * PATCH + kc + kk];
        }
        for (int p = 0; p < 8; ++p) {
            int kr = p * 4 + (tid >> 6);
            int nn = tid & 63;
            Bs[kr][nn] = cw[(size_t)(kc + kr) * D + n0 + nn];
        }
        __syncthreads();
        #pragma unroll
        for (int kk = 0; kk < 32; ++kk) {
            float a[4], bb[4];
            #pragma unroll
            for (int i = 0; i < 4; ++i) a[i] = As[ty * 4 + i][kk];
            #pragma unroll
            for (int j = 0; j < 4; ++j) bb[j] = Bs[kk][tx * 4 + j];
            #pragma unroll
            for (int i = 0; i < 4; ++i)
                #pragma unroll
                for (int j = 0; j < 4; ++j)
                    acc[i][j] = fmaf(a[i], bb[j], acc[i][j]);
        }
        __syncthreads();
    }
    #pragma unroll
    for (int i = 0; i < 4; ++i) {
        int m = m0 + ty * 4 + i;
        int s = m % SEQ;
        int n = n0 + tx * 4;
        float4 v;
        v.x = gelu_exact(acc[i][0]) + pos[(size_t)s * D + n + 0];
        v.y = gelu_exact(acc[i][1]) + pos[(size_t)s * D + n + 1];
        v.z = gelu_exact(acc[i][2]) + pos[(size_t)s * D + n + 2];
        v.w = gelu_exact(acc[i][3]) + pos[(size_t)s * D + n + 3];
        *(float4*)&x[(size_t)m * D + n] = v;
    }
}

// ---------------------------------------------------------------------------
// Kernel 2: per-row mean / rstd (LayerNorm stats). One wave per row.
// ---------------------------------------------------------------------------
__global__ __launch_bounds__(64) void row_stats(
    const float* __restrict__ x, float* __restrict__ st)
{
    const int m = blockIdx.x;
    const int t = threadIdx.x;
    const float* r = x + (size_t)m * D;
    float s = 0.f, q = 0.f;
    #pragma unroll
    for (int i = 0; i < 4; ++i) {
        float v = r[t + 64 * i];
        s += v;
        q += v * v;
    }
    #pragma unroll
    for (int o = 32; o > 0; o >>= 1) {
        s += __shfl_down(s, o);
        q += __shfl_down(q, o);
    }
    if (t == 0) {
        float mu = s * (1.f / 256.f);
        float var = q * (1.f / 256.f) - mu * mu;
        st[2 * m]     = mu;
        st[2 * m + 1] = rsqrtf(var + 1e-5f);
    }
}

// ---------------------------------------------------------------------------
// Kernel 3: fused LN + input-projection GEMM
// ---------------------------------------------------------------------------
__global__ __launch_bounds__(256) void ln_xp_gemm(
    const float* __restrict__ x, const float* __restrict__ st,
    const float* __restrict__ lnsc, const float* __restrict__ lnbi,
    const float* __restrict__ wih, const float* __restrict__ bih,
    float* __restrict__ xp)
{
    __shared__ float As[64][33];
    __shared__ float Bs[32][65];
    __shared__ float sc[D], bi[D];
    const int m0 = blockIdx.x * 64;
    const int n0 = blockIdx.y * 64;
    const int tid = threadIdx.x;
    const int tx = tid & 15;
    const int ty = tid >> 4;
    sc[tid] = lnsc[tid];
    bi[tid] = lnbi[tid];
    float acc[4][4] = {};

    for (int kc = 0; kc < D; kc += 32) {
        for (int p = 0; p < 8; ++p) {
            int mr = p * 8 + (tid >> 5);
            int kk = tid & 31;
            int m = m0 + mr;
            float mu = st[2 * m], rs = st[2 * m + 1];
            float v = x[(size_t)m * D + kc + kk];
            As[mr][kk] = (v - mu) * rs * sc[kc + kk] + bi[kc + kk];
        }
        for (int p = 0; p < 8; ++p) {
            int nr = p * 8 + (tid >> 5);
            int kk = tid & 31;
            Bs[kk][nr] = wih[(size_t)(n0 + nr) * D + kc + kk];
        }
        __syncthreads();
        #pragma unroll
        for (int kk = 0; kk < 32; ++kk) {
            float a[4], bb[4];
            #pragma unroll
            for (int i = 0; i < 4; ++i) a[i] = As[ty * 4 + i][kk];
            #pragma unroll
            for (int j = 0; j < 4; ++j) bb[j] = Bs[kk][tx * 4 + j];
            #pragma unroll
            for (int i = 0; i < 4; ++i)
                #pragma unroll
                for (int j = 0; j < 4; ++j)
                    acc[i][j] = fmaf(a[i], bb[j], acc[i][j]);
        }
        __syncthreads();
    }
    #pragma unroll
    for (int i = 0; i < 4; ++i) {
        int m = m0 + ty * 4 + i;
        int n = n0 + tx * 4;
        float4 v;
        v.x = acc[i][0] + bih[n + 0];
        v.y = acc[i][1] + bih[n + 1];
        v.z = acc[i][2] + bih[n + 2];
        v.w = acc[i][3] + bih[n + 3];
        *(float4*)&xp[(size_t)m * G3 + n] = v;
    }
}

// ---------------------------------------------------------------------------
// Kernel 4: pack w_hh fp32 -> fp16 MFMA B-fragments.
// Tile t (n0=16t, n = gate*256+d over 768), chunk c (k0=32c), lane l, word j:
//   element k = 32c + 8*(l>>4) + 2j,2j+1 ; col n = 16t + (l&15)
//   out[((t*8 + c)*64 + l)*4 + j] = pack(W[n][k], W[n][k+1])   (whh row-major)
// ---------------------------------------------------------------------------
__global__ __launch_bounds__(256) void pack_whh(
    const float* __restrict__ whh, unsigned int* __restrict__ wfrag)
{
    const int idx = blockIdx.x * 256 + threadIdx.x;   // 0..98303
    const int j = idx & 3;
    const int l = (idx >> 2) & 63;
    const int c = (idx >> 8) & 7;
    const int t = idx >> 11;                          // 0..47
    const int n = t * 16 + (l & 15);
    const int k = c * 32 + (l >> 4) * 8 + 2 * j;
    unsigned short lo = __builtin_bit_cast(unsigned short, (_Float16)whh[(size_t)n * D + k]);
    unsigned short hi = __builtin_bit_cast(unsigned short, (_Float16)whh[(size_t)n * D + k + 1]);
    wfrag[idx] = (unsigned int)lo | ((unsigned int)hi << 16);
}

// ---------------------------------------------------------------------------
// Kernel 5: GRU recurrence — SINGLE block per batch, W_hh as AGPR-resident
// MFMA B-fragments (r16-proven, 1.28ms/dispatch), with the serial gates
// phase collapsed.
//
// r16 post-mortem: step 3070cy = MFMA phase ~1550 (pipe-bound: 96 MFMA/SIMD
// x ~19.4cy — invariant to restructuring at 32 CUs) + gates phase
// ~1000-1400 (libm expf x2 + tanhf + 2 exact divides + h_lds round trip,
// on a 1-wave/SIMD critical path). This round attacks ONLY the gates:
//   - sigmoid/tanh on native v_exp_f32 (exp2) + v_rcp (~1ulp each,
//     ~1e-6 output shift vs the passing 2.2e-3) — ~11 inst vs ~60.
//   - h state kept in the gate thread's REGISTER (hreg) — h_lds deleted.
// Everything else (fragments, A-broadcast, gate_lds, h16 pack, 2 bar_lds)
// is r16 verbatim. (Rounds 18-20 were infra flakes — connection died before
// the source was pushed; resubmitted unchanged for clean attribution.)
// ---------------------------------------------------------------------------
__global__ __launch_bounds__(512, 1) void gru_scan_mfma(
    const float* __restrict__ xp, const unsigned int* __restrict__ wfrag,
    const float* __restrict__ bhh, float* __restrict__ x)
{
    __shared__ __align__(16) unsigned int h16_lds[D / 2];  // packed fp16 pairs
    __shared__ float gate_lds[G3];                         // W^T.h results
    const int tid  = threadIdx.x;
    const int w    = tid >> 6;          // wave 0..7
    const int l    = tid & 63;          // lane
    const int d    = tid;               // gate thread's output dim (tid<256)
    const int batch = blockIdx.x;

    // --- resident weights: 48 B-fragments = 192 u32/thread, coalesced ------
    half8 bf[6][8];
    {
        #pragma unroll
        for (int i = 0; i < 6; ++i)
            #pragma unroll
            for (int c = 0; c < 8; ++c) {
                const uint4 v = *(const uint4*)(
                    wfrag + ((size_t)(((w * 6 + i) * 8 + c) * 64 + l)) * 4);
                bf[i][c] = __builtin_bit_cast(half8, v);
            }
    }
    float bh_r = 0.f, bh_z = 0.f, bh_n = 0.f;
    if (tid < D) {
        bh_r = bhh[d];
        bh_z = bhh[D + d];
        bh_n = bhh[2 * D + d];
    }

    const float* xpb = xp + (size_t)batch * SEQ * G3;
    float* xb = x + (size_t)batch * SEQ * D;

    float hreg = 0.f;                   // fp32 h state, register-resident
    if (tid < D / 2) h16_lds[tid] = 0u;
    __syncthreads();

    const int lg = l >> 4;              // lane group 0..3
    for (int t = 0; t < SEQ; ++t) {
        // xp + residual loads early (tid<256); latency hides under MFMA
        float xr = 0.f, xz = 0.f, xn_ = 0.f, xold = 0.f;
        if (tid < D) {
            const float* xpt = xpb + (size_t)t * G3;
            xr   = xpt[d];
            xz   = xpt[D + d];
            xn_  = xpt[2 * D + d];
            xold = xb[(size_t)t * D + d];
        }

        // --- A fragments: h replicated across rows; broadcast LDS reads ----
        half8 af[8];
        #pragma unroll
        for (int c = 0; c < 8; ++c)
            af[c] = __builtin_bit_cast(half8,
                *(const uint4*)(h16_lds + 16 * c + 4 * lg));

        // --- MFMA phase: 6 tiles x 8 K-chunks, C accumulates K in-pipe -----
        #pragma unroll
        for (int i = 0; i < 6; ++i) {
            f32x4 cf = {0.f, 0.f, 0.f, 0.f};
            #pragma unroll
            for (int c = 0; c < 8; ++c)
                cf = __builtin_amdgcn_mfma_f32_16x16x32_f16(af[c], bf[i][c], cf, 0, 0, 0);
            if (l < 16) gate_lds[(w * 6 + i) * 16 + l] = cf[0];  // row 0
        }
        bar_lds();

        // --- gates (tid<256): native exp2/rcp, h in register ---------------
        if (tid < D) {
            float ar = gate_lds[d];
            float az = gate_lds[D + d];
            float an = gate_lds[2 * D + d];
            float r = fast_sigmoid(xr + ar + bh_r);
            float z = fast_sigmoid(xz + az + bh_z);
            float n = fast_tanh(xn_ + r * (an + bh_n));
            float hnew = (1.f - z) * n + z * hreg;
            hreg = hnew;
            // pack (h[d], h[d+1]) -> fp16 pair; neighbors are adjacent lanes
            float hn1 = __shfl_down(hnew, 1);
            if (!(d & 1)) {
                unsigned short l0 = __builtin_bit_cast(unsigned short, (_Float16)hnew);
                unsigned short l1 = __builtin_bit_cast(unsigned short, (_Float16)hn1);
                h16_lds[d >> 1] = (unsigned int)l0 | ((unsigned int)l1 << 16);
            }
            xb[(size_t)t * D + d] = xold + hnew;
        }
        bar_lds();
    }
}

// ---------------------------------------------------------------------------
// Kernel 6: final LN + mean-pool over sequence
// ---------------------------------------------------------------------------
__global__ __launch_bounds__(256) void pool_ln(
    const float* __restrict__ x, const float* __restrict__ st,
    const float* __restrict__ fsc, const float* __restrict__ fbi,
    float* __restrict__ emb)
{
    const int b = blockIdx.x;
    const int d = threadIdx.x;
    float acc = 0.f;
    for (int s = 0; s < SEQ; ++s) {
        int m = b * SEQ + s;
        acc += (x[(size_t)m * D + d] - st[2 * m]) * st[2 * m + 1];
    }
    emb[b * D + d] = (acc * (1.f / (float)SEQ)) * fsc[d] + fbi[d];
}

// ---------------------------------------------------------------------------
// Kernel 7: classification head (tiny). Single block.
// ---------------------------------------------------------------------------
__global__ __launch_bounds__(256) void head_mlp(
    const float* __restrict__ emb, const float* __restrict__ w1,
    const float* __restrict__ b1, const float* __restrict__ w2,
    const float* __restrict__ b2, float* __restrict__ out)
{
    __shared__ float es[NB][D + 1];
    __shared__ float h1[NB][128 + 1];
    const int t = threadIdx.x;
    for (int i = t; i < NB * D; i += 256) es[i / D][i % D] = emb[i];
    __syncthreads();
    for (int i = t; i < NB * 128; i += 256) {
        int bb = i / 128, j = i % 128;
        float a = b1[j];
        for (int k = 0; k < D; ++k) a = fmaf(es[bb][k], w1[(size_t)k * 128 + j], a);
        h1[bb][j] = gelu_exact(a);
    }
    __syncthreads();
    for (int i = t; i < NB * 8; i += 256) {
        int bb = i / 8, c = i % 8;
        float a = b2[c];
        for (int k = 0; k < 128; ++k) a = fmaf(h1[bb][k], w2[(size_t)k * 8 + c], a);
        out[i] = a;
    }
}

// ---------------------------------------------------------------------------
extern "C" void kernel_launch(void* const* d_in, const int* in_sizes, int n_in,
                              void* d_out, int out_size, void* d_ws, size_t ws_size,
                              hipStream_t stream)
{
    const float* wav  = (const float*)d_in[0];
    const float* cw   = (const float*)d_in[1];
    const float* pos  = (const float*)d_in[2];
    const float* lnsc = (const float*)d_in[3];
    const float* lnbi = (const float*)d_in[4];
    const float* wih  = (const float*)d_in[5];
    const float* whh  = (const float*)d_in[6];
    const float* bih  = (const float*)d_in[7];
    const float* bhh  = (const float*)d_in[8];
    const float* fsc  = (const float*)d_in[9];
    const float* fbi  = (const float*)d_in[10];
    const float* hw1  = (const float*)d_in[11];
    const float* hb1  = (const float*)d_in[12];
    const float* hw2  = (const float*)d_in[13];
    const float* hb2  = (const float*)d_in[14];

    float* ws    = (float*)d_ws;
    float* x     = ws;                        // 8,192,000 f
    float* xp    = x + (size_t)M_TOTAL * D;   // 24,576,000 f
    float* st    = xp + (size_t)M_TOTAL * G3; // 64,000 f
    unsigned int* wfrag = (unsigned int*)(st + 2 * M_TOTAL); // 98,304 u32
    float* emb   = (float*)(wfrag + 98304);   // 8,192 f

    conv_gelu_pos<<<dim3(M_TOTAL / 64, D / 64), 256, 0, stream>>>(wav, cw, pos, x);

    for (int l = 0; l < NL; ++l) {
        row_stats<<<M_TOTAL, 64, 0, stream>>>(x, st);
        ln_xp_gemm<<<dim3(M_TOTAL / 64, G3 / 64), 256, 0, stream>>>(
            x, st, lnsc + (size_t)l * D, lnbi + (size_t)l * D,
            wih + (size_t)l * G3 * D, bih + (size_t)l * G3, xp);
        pack_whh<<<384, 256, 0, stream>>>(whh + (size_t)l * G3 * D, wfrag);
        gru_scan_mfma<<<NB, 512, 0, stream>>>(
            xp, wfrag, bhh + (size_t)l * G3, x);
    }

    row_stats<<<M_TOTAL, 64, 0, stream>>>(x, st);
    pool_ln<<<NB, D, 0, stream>>>(x, st, fsc, fbi, emb);
    head_mlp<<<1, 256, 0, stream>>>(emb, hw1, hb1, hw2, hb2, (float*)d_out);
}